// Round 2
// baseline (532.392 us; speedup 1.0000x reference)
//
#include <hip/hip_runtime.h>
#include <math.h>

// DigitCaps dynamic routing, MI355X (gfx950). Round 10: occupancy unlock.
// B=256, I=1152 (dim 8), O=10 (dim 16), 3 routing iters.
//
// R9 post-mortem: recompute-u was right (traffic ~20 MB/kernel) but k_iter
// was latency-bound: 57 us, VALUBusy 50%, Occupancy 23%. Two structural
// occupancy caps: (a) 80-float W fragment -> ~128 combined VGPR+AGPR ->
// 3 waves/SIMD (R6/R7 showed (256,5) spills it); (b) 48 KB LDS -> 3
// blocks/CU. This round removes both:
//  - o-split threads: t = (il 8) x (oh 2) x (d 16). Each thread holds 5 o's
//    of W (40 floats). Softmax crosses the oh halves with two shfl_xor(16)
//    (max partial + sum-of-exp partial). Register need ~85 -> (256,5) safe.
//  - single pacc[32][160] (20 KB) accumulated with LDS atomicAdd
//    (ds_add_f32), warp-staggered bb order to avoid same-address contention.
//    LDS 28 KB total -> 5 blocks/CU.
//  - b-tile 32 (W L2 traffic halves to ~46 MB/pass), i-tile 8 -> partial
//    buffer 23.6 MB (acceptable: ~7 us extra HBM across pipeline).
//  - k_pass<0> (uniform c, no softmax) replaces k_uhat_p0; k_reduce uses
//    4 teams x 36-deep chains (was 1x72 at 9% occupancy).
//
// Pipeline:
//  K1 k_pass<0>:   partial = sum_i u
//  K2 k_reduce<0>: vsumg = squash(0.1*sum144 partial)   (transposed layout)
//  K3 k_pass<1>:   recompute u, c=softmax(u.vsum), partial = sum_i c*u
//  K4 k_reduce<1>: vsumg += squash(sum144)
//  K5 k_pass<1>:   same as K3 (vsum = v0+v1 via b_ij identity)
//  K6 k_reduce<2>: out = squash(sum144)

constexpr int Bc  = 256;
constexpr int Ic  = 1152;
constexpr int Oc  = 10;
constexpr int DOc = 16;
constexpr int ODc = 160;
constexpr int IT  = 144;   // i-tiles of 8
constexpr int BT  = 8;     // b-tiles of 32
constexpr int BB  = 32;    // b per block

// Sum over the aligned 16-lane group, result in all 16 lanes. Pure VALU (DPP).
__device__ __forceinline__ float dpp16_sum(float v) {
    int s;
    s = __builtin_amdgcn_update_dpp(0, __float_as_int(v), 0xB1, 0xF, 0xF, true);
    v += __int_as_float(s);
    s = __builtin_amdgcn_update_dpp(0, __float_as_int(v), 0x4E, 0xF, 0xF, true);
    v += __int_as_float(s);
    s = __builtin_amdgcn_update_dpp(0, __float_as_int(v), 0x124, 0xF, 0xF, true);
    v += __int_as_float(s);
    s = __builtin_amdgcn_update_dpp(0, __float_as_int(v), 0x128, 0xF, 0xF, true);
    v += __int_as_float(s);
    return v;
}

// ---------------------------------------------------------------- k_pass
// One routing pass. Thread layout: t = il*32 + oh*16 + d.
//   il (0..7): input capsule within the 8-i tile (i = itile*8 + il)
//   oh (0..1): o-half; this thread owns o = oh*5 .. oh*5+4
//   d  (0..15): out-capsule dim
// PASS==0: uniform coupling (a = u); else logits u.vsum -> softmax -> c*u.
// vsum layout (transposed): vsum[b*256 + d*16 + oh*8 + oq], slots 5..7/13..15
// unused -> each thread reads one float4 + one float, 16B aligned.
template <int PASS>
__global__ __launch_bounds__(256, 5) void k_pass(const float* __restrict__ x,
                                                 const float* __restrict__ W,
                                                 const float* __restrict__ vsum,
                                                 float* __restrict__ spart) {
    const int bx    = blockIdx.x;
    const int itile = bx % IT;
    const int btile = bx / IT;
    const int t     = threadIdx.x;
    const int d     = t & 15;
    const int oh    = (t >> 4) & 1;
    const int il    = t >> 5;
    const int w     = t >> 6;
    const int i     = itile * 8 + il;
    const int b0    = btile * BB;

    __shared__ __align__(16) float xs[BB * 64];     //  8 KB [bb][il*8+k]
    __shared__ __align__(16) float pacc[BB * ODc];  // 20 KB [bb][o*16+d]

    // stage x[b0:b0+32][itile*8:+8][8] (contiguous 64 floats per b)
#pragma unroll
    for (int j = 0; j < 2; ++j) {
        int e  = t + j * 256;
        int bb = e >> 4;
        int r  = e & 15;
        ((float4*)xs)[e] =
            ((const float4*)(x + (size_t)(b0 + bb) * (Ic * 8) + itile * 64))[r];
    }

    // W fragment for (i, own 5 o's, d): 40 floats in registers
    float4 wr[10];
    {
        const float4* wp =
            (const float4*)(W + (((size_t)i * Oc + oh * 5) * DOc + d) * 8);
#pragma unroll
        for (int oq = 0; oq < 5; ++oq) {
            wr[2 * oq]     = wp[oq * 32];
            wr[2 * oq + 1] = wp[oq * 32 + 1];
        }
    }
    // zero the shared accumulator
#pragma unroll
    for (int j = 0; j < 20; ++j) pacc[t + j * 256] = 0.f;
    __syncthreads();

#pragma unroll 1
    for (int bbi = 0; bbi < BB; ++bbi) {
        const int bb = (bbi + w * 8) & (BB - 1);   // stagger warps across bb
        const float4 xa = *((const float4*)(xs + bb * 64 + il * 8));
        const float4 xb = *((const float4*)(xs + bb * 64 + il * 8 + 4));
        float u[5];
#pragma unroll
        for (int oq = 0; oq < 5; ++oq) {
            float4 w0 = wr[2 * oq], w1 = wr[2 * oq + 1];
            u[oq] = w0.x * xa.x + w0.y * xa.y + w0.z * xa.z + w0.w * xa.w +
                    w1.x * xb.x + w1.y * xb.y + w1.z * xb.z + w1.w * xb.w;
        }
        float a5[5];
        if constexpr (PASS == 0) {
#pragma unroll
            for (int oq = 0; oq < 5; ++oq) a5[oq] = u[oq];
        } else {
            const float* vb = vsum + (size_t)(b0 + bb) * 256 + d * 16 + oh * 8;
            const float4 v4 = *((const float4*)vb);
            const float  v1 = vb[4];
            // logits for own 5 o's: 16-lane DPP reduce over d
            float l[5];
            l[0] = dpp16_sum(u[0] * v4.x);
            l[1] = dpp16_sum(u[1] * v4.y);
            l[2] = dpp16_sum(u[2] * v4.z);
            l[3] = dpp16_sum(u[3] * v4.w);
            l[4] = dpp16_sum(u[4] * v1);
            // softmax over all 10: exchange max / sum-of-exp with other half
            float mo = fmaxf(fmaxf(fmaxf(l[0], l[1]), fmaxf(l[2], l[3])), l[4]);
            float m  = fmaxf(mo, __shfl_xor(mo, 16));
            float se = 0.f;
#pragma unroll
            for (int oq = 0; oq < 5; ++oq) {
                l[oq] = __expf(l[oq] - m);
                se += l[oq];
            }
            se += __shfl_xor(se, 16);
            const float inv = 1.f / se;
#pragma unroll
            for (int oq = 0; oq < 5; ++oq) a5[oq] = (l[oq] * inv) * u[oq];
        }
        // reduce over il: pair-sum in-warp, then LDS atomic across warps
#pragma unroll
        for (int oq = 0; oq < 5; ++oq) {
            float a = a5[oq];
            a += __shfl_xor(a, 32);
            if ((t & 63) < 32)
                atomicAdd(&pacc[bb * ODc + (oh * 5 + oq) * 16 + d], a);
        }
    }
    __syncthreads();
#pragma unroll
    for (int j = 0; j < 20; ++j) {
        int e = t + j * 256;
        spart[(size_t)itile * (Bc * ODc) + b0 * ODc + e] = pacc[e];
    }
}

// ---------------------------------------------------------------- k_reduce
// Sum 144 itile-partials -> s[b][160], squash; 4 teams of 256 threads each
// chain 36 strided loads (was 1x72 at 9% occupancy).
//  P==0: vsumg = v (s scaled 0.1);  P==1: vsumg += v;  P==2: out = v.
template <int P>
__global__ __launch_bounds__(1024) void k_reduce(const float* __restrict__ part,
                                                 float* __restrict__ vsumg,
                                                 float* __restrict__ out) {
    const int b = blockIdx.x;
    const int t = threadIdx.x;
    __shared__ float red4[4 * ODc];
    const int team = t >> 8, tt = t & 255;
    if (tt < ODc) {
        float s = 0.f;
        const float* pb =
            part + (size_t)team * 36 * (Bc * ODc) + (size_t)b * ODc + tt;
#pragma unroll
        for (int p = 0; p < 36; ++p) s += pb[(size_t)p * (Bc * ODc)];
        red4[team * ODc + tt] = s;
    }
    __syncthreads();
    if (t < ODc) {
        float s = red4[t] + red4[ODc + t] + red4[2 * ODc + t] + red4[3 * ODc + t];
        if (P == 0) s *= 0.1f;
        float sq = dpp16_sum(s * s);
        float v = s * (sq / ((1.f + sq) * sqrtf(sq)));
        if constexpr (P == 2) {
            out[(size_t)b * ODc + t] = v;
        } else {
            const int o = t >> 4, dd = t & 15;
            float* vp = vsumg + (size_t)b * 256 + dd * 16 + (o >= 5 ? 3 + o : o);
            if constexpr (P == 0) *vp = v;
            else                  *vp += v;
        }
    }
}

// ---------------------------------------------------------------- fallback
__global__ void __launch_bounds__(1024, 4)
digitcaps_fallback(const float* __restrict__ x, const float* __restrict__ W,
                   float* __restrict__ out) {
    const int b = blockIdx.x, t = threadIdx.x;
    const int lane = t & 63, wid = t >> 6, d = t & 15, iblk = t >> 4;
    __shared__ __align__(16) float xs[Ic * 8];
    __shared__ __align__(16) float red[16 * ODc];
    __shared__ __align__(16) float svec[ODc], vcur[ODc], vsum[ODc];
    {
        const float4* xg = (const float4*)(x + (size_t)b * (Ic * 8));
        float4* xl = (float4*)xs;
        for (int j = t; j < Ic * 2; j += 1024) xl[j] = xg[j];
    }
    if (t < ODc) vsum[t] = 0.f;
    __syncthreads();
    float acc[Oc], vsr[Oc];
    for (int it = 0; it < 3; ++it) {
#pragma unroll
        for (int o = 0; o < Oc; ++o) { acc[o] = 0.f; vsr[o] = vsum[o * 16 + d]; }
#pragma unroll 1
        for (int chk = 0; chk < 18; ++chk) {
            const int i = chk * 64 + iblk;
            const float4 xa = ((const float4*)(xs + i * 8))[0];
            const float4 xb = ((const float4*)(xs + i * 8))[1];
            const float* wb = W + (((size_t)i * Oc) * DOc + d) * 8;
            float uo[Oc];
#pragma unroll
            for (int o = 0; o < Oc; ++o) {
                const float4* wp = (const float4*)(wb + o * 128);
                float4 w0 = wp[0], w1 = wp[1];
                uo[o] = w0.x * xa.x + w0.y * xa.y + w0.z * xa.z + w0.w * xa.w +
                        w1.x * xb.x + w1.y * xb.y + w1.z * xb.z + w1.w * xb.w;
            }
            float cc[Oc];
            if (it > 0) {
#pragma unroll
                for (int o = 0; o < Oc; ++o) cc[o] = dpp16_sum(uo[o] * vsr[o]);
                float m = cc[0];
#pragma unroll
                for (int o = 1; o < Oc; ++o) m = fmaxf(m, cc[o]);
                float se = 0.f;
#pragma unroll
                for (int o = 0; o < Oc; ++o) { cc[o] = __expf(cc[o] - m); se += cc[o]; }
                float inv = 1.f / se;
#pragma unroll
                for (int o = 0; o < Oc; ++o) acc[o] += cc[o] * inv * uo[o];
            } else {
#pragma unroll
                for (int o = 0; o < Oc; ++o) acc[o] += 0.1f * uo[o];
            }
        }
#pragma unroll
        for (int o = 0; o < Oc; ++o) {
            float a = acc[o];
            a += __shfl_xor(a, 16);
            a += __shfl_xor(a, 32);
            if (lane < 16) red[wid * ODc + o * 16 + lane] = a;
        }
        __syncthreads();
        if (t < ODc) {
            float s = 0.f;
#pragma unroll
            for (int w = 0; w < 16; ++w) s += red[w * ODc + t];
            svec[t] = s;
        }
        __syncthreads();
        if (t < Oc) {
            float sq = 0.f;
#pragma unroll
            for (int dd = 0; dd < DOc; ++dd) sq += svec[t * 16 + dd] * svec[t * 16 + dd];
            float sc = sq / ((1.f + sq) * sqrtf(sq));
#pragma unroll
            for (int dd = 0; dd < DOc; ++dd) {
                float v = svec[t * 16 + dd] * sc;
                vcur[t * 16 + dd] = v;
                vsum[t * 16 + dd] += v;
            }
        }
        __syncthreads();
    }
    if (t < ODc) out[(size_t)b * ODc + t] = vcur[t];
}

// ---------------------------------------------------------------- launcher
extern "C" void kernel_launch(void* const* d_in, const int* in_sizes, int n_in,
                              void* d_out, int out_size, void* d_ws, size_t ws_size,
                              hipStream_t stream) {
    (void)in_sizes; (void)n_in; (void)out_size;
    const float* x = (const float*)d_in[0];   // [256,1152,8]
    const float* W = (const float*)d_in[1];   // [1152,10,16,8]
    float* out     = (float*)d_out;           // [256,10,16]

    const size_t PART_B = (size_t)IT * Bc * ODc * sizeof(float); // 23.59 MB
    const size_t VS_B   = (size_t)Bc * 256 * sizeof(float);      //  0.26 MB

    float* partial = (float*)d_ws;
    float* vsumg   = (float*)((char*)d_ws + PART_B);

    if (ws_size >= PART_B + VS_B) {
        hipLaunchKernelGGL((k_pass<0>), dim3(IT * BT), dim3(256), 0, stream,
                           x, W, nullptr, partial);
        hipLaunchKernelGGL((k_reduce<0>), dim3(Bc), dim3(1024), 0, stream,
                           partial, vsumg, nullptr);
        hipLaunchKernelGGL((k_pass<1>), dim3(IT * BT), dim3(256), 0, stream,
                           x, W, vsumg, partial);
        hipLaunchKernelGGL((k_reduce<1>), dim3(Bc), dim3(1024), 0, stream,
                           partial, vsumg, nullptr);
        hipLaunchKernelGGL((k_pass<1>), dim3(IT * BT), dim3(256), 0, stream,
                           x, W, vsumg, partial);
        hipLaunchKernelGGL((k_reduce<2>), dim3(Bc), dim3(1024), 0, stream,
                           partial, nullptr, out);
    } else {
        hipLaunchKernelGGL(digitcaps_fallback, dim3(Bc), dim3(1024), 0, stream,
                           x, W, out);
    }
}

// Round 3
// 191.979 us; speedup vs baseline: 2.7732x; 2.7732x over previous
//
#include <hip/hip_runtime.h>
#include <math.h>

// DigitCaps dynamic routing, MI355X (gfx950). Round 11.
// B=256, I=1152 (dim 8), O=10 (dim 16), 3 routing iters.
//
// R10 post-mortem: (256,5) spilled the 40-float W fragment to scratch
// (VGPR_Count 44, 159 us) -- third confirmation that the unified-RF budget
// at 5 waves/EU (102 regs) cannot hold a W fragment. LDS atomics added
// serialization on top.
//
// R11 = R9's proven race-free dataflow + the o-split fragment at the
// proven-safe occupancy point:
//  - thread = (il 8, oh 2, d 16); W frag = 5 o x 8 k = 40 floats;
//    launch_bounds(256,4) -> 128 unified regs, ~88 live -> no spill,
//    no AGPR round-trips (R9's 80-float frag cost ~160 accvgpr moves/bb).
//  - il-pair reduced in-wave by shfl_xor(32); cross-warp by per-warp LDS
//    slabs pacc[4][16][160] (plain stores, disjoint, ONE syncthreads).
//  - BB=16 b per block, i-tile 8 -> 144 partials (23.6 MB/pass round trip,
//    ~10 us of HBM per pass -- acceptable vs the VALU win).
//  - k_reduce: 1024 thr, 4 teams x 36-deep chains (R10's, measured fast).
//
// Pipeline:
//  K1 k_pass<0>:   partial = sum_i u            (uniform c, no softmax)
//  K2 k_reduce<0>: vsumg = squash(0.1*sum144)   (transposed o-in-8-slot)
//  K3 k_pass<1>:   recompute u, c=softmax(u.vsum), partial = sum_i c*u
//  K4 k_reduce<1>: vsumg += squash(sum144)
//  K5 k_pass<1>:   same (b_ij identity: logits = u.vsum)
//  K6 k_reduce<2>: out = squash(sum144)

constexpr int Bc  = 256;
constexpr int Ic  = 1152;
constexpr int Oc  = 10;
constexpr int DOc = 16;
constexpr int ODc = 160;
constexpr int IT  = 144;   // i-tiles of 8
constexpr int BT  = 16;    // b-tiles of 16
constexpr int BB  = 16;    // b per block

// Sum over the aligned 16-lane group, result in all 16 lanes. Pure VALU (DPP).
__device__ __forceinline__ float dpp16_sum(float v) {
    int s;
    s = __builtin_amdgcn_update_dpp(0, __float_as_int(v), 0xB1, 0xF, 0xF, true);
    v += __int_as_float(s);
    s = __builtin_amdgcn_update_dpp(0, __float_as_int(v), 0x4E, 0xF, 0xF, true);
    v += __int_as_float(s);
    s = __builtin_amdgcn_update_dpp(0, __float_as_int(v), 0x124, 0xF, 0xF, true);
    v += __int_as_float(s);
    s = __builtin_amdgcn_update_dpp(0, __float_as_int(v), 0x128, 0xF, 0xF, true);
    v += __int_as_float(s);
    return v;
}

// ---------------------------------------------------------------- k_pass
// Thread layout: t = il*32 + oh*16 + d.
//   il (0..7): input capsule within the 8-i tile; warp w holds il {2w,2w+1}
//   oh (0..1): o-half; thread owns o = oh*5 .. oh*5+4
//   d  (0..15): out-capsule dim (lane bits 0..3 -> dpp16 reduces over d)
// vsum layout (transposed): vsum[b*256 + d*16 + oh*8 + oq] (slots 5..7
// and 13..15 unused) -> one aligned float4 + one float per thread per bb.
template <int PASS>
__global__ __launch_bounds__(256, 4) void k_pass(const float* __restrict__ x,
                                                 const float* __restrict__ W,
                                                 const float* __restrict__ vsum,
                                                 float* __restrict__ spart) {
    const int bx    = blockIdx.x;
    const int itile = bx % IT;
    const int btile = bx / IT;
    const int t     = threadIdx.x;
    const int d     = t & 15;
    const int oh    = (t >> 4) & 1;
    const int il    = t >> 5;
    const int w     = t >> 6;
    const int i     = itile * 8 + il;
    const int b0    = btile * BB;

    __shared__ __align__(16) float xs[BB * 64];         //  4 KB [bb][il*8+k]
    __shared__ __align__(16) float pacc[4 * BB * ODc];  // 40 KB [w][bb][od]

    // stage x[b0:b0+16][itile*8:+8][8] = 256 float4s, one per thread
    {
        int bb = t >> 4;
        int r  = t & 15;
        ((float4*)xs)[t] =
            ((const float4*)(x + (size_t)(b0 + bb) * (Ic * 8) + itile * 64))[r];
    }

    // W fragment for (i, own 5 o's, d): 40 floats in registers
    float4 wr[10];
    {
        const float4* wp =
            (const float4*)(W + (((size_t)i * Oc + oh * 5) * DOc + d) * 8);
#pragma unroll
        for (int oq = 0; oq < 5; ++oq) {
            wr[2 * oq]     = wp[oq * 32];
            wr[2 * oq + 1] = wp[oq * 32 + 1];
        }
    }
    __syncthreads();

#pragma unroll 1
    for (int bb = 0; bb < BB; ++bb) {
        const float4 xa = *((const float4*)(xs + bb * 64 + il * 8));
        const float4 xb = *((const float4*)(xs + bb * 64 + il * 8 + 4));
        float u[5];
#pragma unroll
        for (int oq = 0; oq < 5; ++oq) {
            float4 w0 = wr[2 * oq], w1 = wr[2 * oq + 1];
            u[oq] = w0.x * xa.x + w0.y * xa.y + w0.z * xa.z + w0.w * xa.w +
                    w1.x * xb.x + w1.y * xb.y + w1.z * xb.z + w1.w * xb.w;
        }
        float a5[5];
        if constexpr (PASS == 0) {
#pragma unroll
            for (int oq = 0; oq < 5; ++oq) a5[oq] = u[oq];
        } else {
            const float* vb = vsum + (size_t)(b0 + bb) * 256 + d * 16 + oh * 8;
            const float4 v4 = *((const float4*)vb);
            const float  v1 = vb[4];
            // logits for own 5 o's: DPP reduce over the 16 d-lanes
            float l[5];
            l[0] = dpp16_sum(u[0] * v4.x);
            l[1] = dpp16_sum(u[1] * v4.y);
            l[2] = dpp16_sum(u[2] * v4.z);
            l[3] = dpp16_sum(u[3] * v4.w);
            l[4] = dpp16_sum(u[4] * v1);
            // softmax over 10: cross the oh halves with shfl_xor(16)
            float mo = fmaxf(fmaxf(fmaxf(l[0], l[1]), fmaxf(l[2], l[3])), l[4]);
            float m  = fmaxf(mo, __shfl_xor(mo, 16));
            float se = 0.f;
#pragma unroll
            for (int oq = 0; oq < 5; ++oq) {
                l[oq] = __expf(l[oq] - m);
                se += l[oq];
            }
            se += __shfl_xor(se, 16);
            const float inv = 1.f / se;
#pragma unroll
            for (int oq = 0; oq < 5; ++oq) a5[oq] = (l[oq] * inv) * u[oq];
        }
        // il-pair reduce in-wave; lanes<32 write warp slab (race-free)
#pragma unroll
        for (int oq = 0; oq < 5; ++oq) {
            float a = a5[oq];
            a += __shfl_xor(a, 32);
            if ((t & 63) < 32)
                pacc[(w * BB + bb) * ODc + (oh * 5 + oq) * 16 + d] = a;
        }
    }
    __syncthreads();
    // sum the 4 warp slabs -> per-itile partial
#pragma unroll
    for (int j = 0; j < 10; ++j) {
        int e = t + j * 256;
        float s = pacc[e] + pacc[2560 + e] + pacc[5120 + e] + pacc[7680 + e];
        spart[(size_t)itile * (Bc * ODc) + b0 * ODc + e] = s;
    }
}

// ---------------------------------------------------------------- k_reduce
// Sum 144 itile-partials -> s[b][160], squash; 4 teams x 36-deep chains.
//  P==0: vsumg = v (s scaled 0.1);  P==1: vsumg += v;  P==2: out = v.
template <int P>
__global__ __launch_bounds__(1024) void k_reduce(const float* __restrict__ part,
                                                 float* __restrict__ vsumg,
                                                 float* __restrict__ out) {
    const int b = blockIdx.x;
    const int t = threadIdx.x;
    __shared__ float red4[4 * ODc];
    const int team = t >> 8, tt = t & 255;
    if (tt < ODc) {
        float s = 0.f;
        const float* pb =
            part + (size_t)team * 36 * (Bc * ODc) + (size_t)b * ODc + tt;
#pragma unroll
        for (int p = 0; p < 36; ++p) s += pb[(size_t)p * (Bc * ODc)];
        red4[team * ODc + tt] = s;
    }
    __syncthreads();
    if (t < ODc) {
        float s = red4[t] + red4[ODc + t] + red4[2 * ODc + t] + red4[3 * ODc + t];
        if (P == 0) s *= 0.1f;
        float sq = dpp16_sum(s * s);
        float v = s * (sq / ((1.f + sq) * sqrtf(sq)));
        if constexpr (P == 2) {
            out[(size_t)b * ODc + t] = v;
        } else {
            const int o = t >> 4, dd = t & 15;
            float* vp = vsumg + (size_t)b * 256 + dd * 16 + (o >= 5 ? 3 + o : o);
            if constexpr (P == 0) *vp = v;
            else                  *vp += v;
        }
    }
}

// ---------------------------------------------------------------- fallback
__global__ void __launch_bounds__(1024, 4)
digitcaps_fallback(const float* __restrict__ x, const float* __restrict__ W,
                   float* __restrict__ out) {
    const int b = blockIdx.x, t = threadIdx.x;
    const int lane = t & 63, wid = t >> 6, d = t & 15, iblk = t >> 4;
    __shared__ __align__(16) float xs[Ic * 8];
    __shared__ __align__(16) float red[16 * ODc];
    __shared__ __align__(16) float svec[ODc], vcur[ODc], vsum[ODc];
    {
        const float4* xg = (const float4*)(x + (size_t)b * (Ic * 8));
        float4* xl = (float4*)xs;
        for (int j = t; j < Ic * 2; j += 1024) xl[j] = xg[j];
    }
    if (t < ODc) vsum[t] = 0.f;
    __syncthreads();
    float acc[Oc], vsr[Oc];
    for (int it = 0; it < 3; ++it) {
#pragma unroll
        for (int o = 0; o < Oc; ++o) { acc[o] = 0.f; vsr[o] = vsum[o * 16 + d]; }
#pragma unroll 1
        for (int chk = 0; chk < 18; ++chk) {
            const int i = chk * 64 + iblk;
            const float4 xa = ((const float4*)(xs + i * 8))[0];
            const float4 xb = ((const float4*)(xs + i * 8))[1];
            const float* wb = W + (((size_t)i * Oc) * DOc + d) * 8;
            float uo[Oc];
#pragma unroll
            for (int o = 0; o < Oc; ++o) {
                const float4* wp = (const float4*)(wb + o * 128);
                float4 w0 = wp[0], w1 = wp[1];
                uo[o] = w0.x * xa.x + w0.y * xa.y + w0.z * xa.z + w0.w * xa.w +
                        w1.x * xb.x + w1.y * xb.y + w1.z * xb.z + w1.w * xb.w;
            }
            float cc[Oc];
            if (it > 0) {
#pragma unroll
                for (int o = 0; o < Oc; ++o) cc[o] = dpp16_sum(uo[o] * vsr[o]);
                float m = cc[0];
#pragma unroll
                for (int o = 1; o < Oc; ++o) m = fmaxf(m, cc[o]);
                float se = 0.f;
#pragma unroll
                for (int o = 0; o < Oc; ++o) { cc[o] = __expf(cc[o] - m); se += cc[o]; }
                float inv = 1.f / se;
#pragma unroll
                for (int o = 0; o < Oc; ++o) acc[o] += cc[o] * inv * uo[o];
            } else {
#pragma unroll
                for (int o = 0; o < Oc; ++o) acc[o] += 0.1f * uo[o];
            }
        }
#pragma unroll
        for (int o = 0; o < Oc; ++o) {
            float a = acc[o];
            a += __shfl_xor(a, 16);
            a += __shfl_xor(a, 32);
            if (lane < 16) red[wid * ODc + o * 16 + lane] = a;
        }
        __syncthreads();
        if (t < ODc) {
            float s = 0.f;
#pragma unroll
            for (int w = 0; w < 16; ++w) s += red[w * ODc + t];
            svec[t] = s;
        }
        __syncthreads();
        if (t < Oc) {
            float sq = 0.f;
#pragma unroll
            for (int dd = 0; dd < DOc; ++dd) sq += svec[t * 16 + dd] * svec[t * 16 + dd];
            float sc = sq / ((1.f + sq) * sqrtf(sq));
#pragma unroll
            for (int dd = 0; dd < DOc; ++dd) {
                float v = svec[t * 16 + dd] * sc;
                vcur[t * 16 + dd] = v;
                vsum[t * 16 + dd] += v;
            }
        }
        __syncthreads();
    }
    if (t < ODc) out[(size_t)b * ODc + t] = vcur[t];
}

// ---------------------------------------------------------------- launcher
extern "C" void kernel_launch(void* const* d_in, const int* in_sizes, int n_in,
                              void* d_out, int out_size, void* d_ws, size_t ws_size,
                              hipStream_t stream) {
    (void)in_sizes; (void)n_in; (void)out_size;
    const float* x = (const float*)d_in[0];   // [256,1152,8]
    const float* W = (const float*)d_in[1];   // [1152,10,16,8]
    float* out     = (float*)d_out;           // [256,10,16]

    const size_t PART_B = (size_t)IT * Bc * ODc * sizeof(float); // 23.59 MB
    const size_t VS_B   = (size_t)Bc * 256 * sizeof(float);      //  0.26 MB

    float* partial = (float*)d_ws;
    float* vsumg   = (float*)((char*)d_ws + PART_B);

    if (ws_size >= PART_B + VS_B) {
        hipLaunchKernelGGL((k_pass<0>), dim3(IT * BT), dim3(256), 0, stream,
                           x, W, nullptr, partial);
        hipLaunchKernelGGL((k_reduce<0>), dim3(Bc), dim3(1024), 0, stream,
                           partial, vsumg, nullptr);
        hipLaunchKernelGGL((k_pass<1>), dim3(IT * BT), dim3(256), 0, stream,
                           x, W, vsumg, partial);
        hipLaunchKernelGGL((k_reduce<1>), dim3(Bc), dim3(1024), 0, stream,
                           partial, vsumg, nullptr);
        hipLaunchKernelGGL((k_pass<1>), dim3(IT * BT), dim3(256), 0, stream,
                           x, W, vsumg, partial);
        hipLaunchKernelGGL((k_reduce<2>), dim3(Bc), dim3(1024), 0, stream,
                           partial, nullptr, out);
    } else {
        hipLaunchKernelGGL(digitcaps_fallback, dim3(Bc), dim3(1024), 0, stream,
                           x, W, out);
    }
}

// Round 4
// 171.978 us; speedup vs baseline: 3.0957x; 1.1163x over previous
//
#include <hip/hip_runtime.h>
#include <math.h>

// DigitCaps dynamic routing, MI355X (gfx950). Round 12: occupancy via LDS diet.
// B=256, I=1152 (dim 8), O=10 (dim 16), 3 routing iters.
//
// R11 post-mortem: pass0 (no softmax) == pass1 == 52 us despite 2x VALU
// difference => latency-bound, not VALU-bound. Occupancy 26% (44 KB LDS ->
// 3 blocks/CU) leaves dependency chains exposed. VGPR 68, no spill.
//
// R12: keep R11's dataflow EXACTLY (o-split threads, 40-float W frag,
// race-free per-warp LDS slabs, one syncthreads), but:
//  - BB 16 -> 8: pacc[4][8][160]=20 KB + xs 2 KB = 22.5 KB LDS
//    -> LDS admits 7 blocks/CU; launch_bounds(256,6) (reg budget 85 vs
//    measured 68) -> 24 waves/CU = 75% occupancy cap (was 37.5%).
//  - grid 4608 blocks; W L2 traffic doubles (~188 MB/pass, ~+3 us from L2,
//    HBM unchanged -- W is cache-resident per R9-R11 FETCH counters).
//  - partial buffer & k_reduce unchanged.
//
// Pipeline:
//  K1 k_pass<0>:   partial = sum_i u            (uniform c, no softmax)
//  K2 k_reduce<0>: vsumg = squash(0.1*sum144)   (transposed o-in-8-slot)
//  K3 k_pass<1>:   recompute u, c=softmax(u.vsum), partial = sum_i c*u
//  K4 k_reduce<1>: vsumg += squash(sum144)
//  K5 k_pass<1>:   same (b_ij identity: logits = u.vsum)
//  K6 k_reduce<2>: out = squash(sum144)

constexpr int Bc  = 256;
constexpr int Ic  = 1152;
constexpr int Oc  = 10;
constexpr int DOc = 16;
constexpr int ODc = 160;
constexpr int IT  = 144;   // i-tiles of 8
constexpr int BT  = 32;    // b-tiles of 8
constexpr int BB  = 8;     // b per block

// Sum over the aligned 16-lane group, result in all 16 lanes. Pure VALU (DPP).
__device__ __forceinline__ float dpp16_sum(float v) {
    int s;
    s = __builtin_amdgcn_update_dpp(0, __float_as_int(v), 0xB1, 0xF, 0xF, true);
    v += __int_as_float(s);
    s = __builtin_amdgcn_update_dpp(0, __float_as_int(v), 0x4E, 0xF, 0xF, true);
    v += __int_as_float(s);
    s = __builtin_amdgcn_update_dpp(0, __float_as_int(v), 0x124, 0xF, 0xF, true);
    v += __int_as_float(s);
    s = __builtin_amdgcn_update_dpp(0, __float_as_int(v), 0x128, 0xF, 0xF, true);
    v += __int_as_float(s);
    return v;
}

// ---------------------------------------------------------------- k_pass
// Thread layout: t = il*32 + oh*16 + d.
//   il (0..7): input capsule within the 8-i tile; warp w holds il {2w,2w+1}
//   oh (0..1): o-half; thread owns o = oh*5 .. oh*5+4
//   d  (0..15): out-capsule dim (lane bits 0..3 -> dpp16 reduces over d)
// vsum layout (transposed): vsum[b*256 + d*16 + oh*8 + oq] (slots 5..7
// and 13..15 unused) -> one aligned float4 + one float per thread per bb.
template <int PASS>
__global__ __launch_bounds__(256, 6) void k_pass(const float* __restrict__ x,
                                                 const float* __restrict__ W,
                                                 const float* __restrict__ vsum,
                                                 float* __restrict__ spart) {
    const int bx    = blockIdx.x;
    const int itile = bx % IT;
    const int btile = bx / IT;
    const int t     = threadIdx.x;
    const int d     = t & 15;
    const int oh    = (t >> 4) & 1;
    const int il    = t >> 5;
    const int w     = t >> 6;
    const int i     = itile * 8 + il;
    const int b0    = btile * BB;

    __shared__ __align__(16) float xs[BB * 64];         //  2 KB [bb][il*8+k]
    __shared__ __align__(16) float pacc[4 * BB * ODc];  // 20 KB [w][bb][od]

    // stage x[b0:b0+8][itile*8:+8][8] = 128 float4s
    if (t < 128) {
        int bb = t >> 4;
        int r  = t & 15;
        ((float4*)xs)[t] =
            ((const float4*)(x + (size_t)(b0 + bb) * (Ic * 8) + itile * 64))[r];
    }

    // W fragment for (i, own 5 o's, d): 40 floats in registers
    float4 wr[10];
    {
        const float4* wp =
            (const float4*)(W + (((size_t)i * Oc + oh * 5) * DOc + d) * 8);
#pragma unroll
        for (int oq = 0; oq < 5; ++oq) {
            wr[2 * oq]     = wp[oq * 32];
            wr[2 * oq + 1] = wp[oq * 32 + 1];
        }
    }
    __syncthreads();

#pragma unroll 1
    for (int bb = 0; bb < BB; ++bb) {
        const float4 xa = *((const float4*)(xs + bb * 64 + il * 8));
        const float4 xb = *((const float4*)(xs + bb * 64 + il * 8 + 4));
        float u[5];
#pragma unroll
        for (int oq = 0; oq < 5; ++oq) {
            float4 w0 = wr[2 * oq], w1 = wr[2 * oq + 1];
            u[oq] = w0.x * xa.x + w0.y * xa.y + w0.z * xa.z + w0.w * xa.w +
                    w1.x * xb.x + w1.y * xb.y + w1.z * xb.z + w1.w * xb.w;
        }
        float a5[5];
        if constexpr (PASS == 0) {
#pragma unroll
            for (int oq = 0; oq < 5; ++oq) a5[oq] = u[oq];
        } else {
            const float* vb = vsum + (size_t)(b0 + bb) * 256 + d * 16 + oh * 8;
            const float4 v4 = *((const float4*)vb);
            const float  v1 = vb[4];
            // logits for own 5 o's: DPP reduce over the 16 d-lanes
            float l[5];
            l[0] = dpp16_sum(u[0] * v4.x);
            l[1] = dpp16_sum(u[1] * v4.y);
            l[2] = dpp16_sum(u[2] * v4.z);
            l[3] = dpp16_sum(u[3] * v4.w);
            l[4] = dpp16_sum(u[4] * v1);
            // softmax over 10: cross the oh halves with shfl_xor(16)
            float mo = fmaxf(fmaxf(fmaxf(l[0], l[1]), fmaxf(l[2], l[3])), l[4]);
            float m  = fmaxf(mo, __shfl_xor(mo, 16));
            float se = 0.f;
#pragma unroll
            for (int oq = 0; oq < 5; ++oq) {
                l[oq] = __expf(l[oq] - m);
                se += l[oq];
            }
            se += __shfl_xor(se, 16);
            const float inv = 1.f / se;
#pragma unroll
            for (int oq = 0; oq < 5; ++oq) a5[oq] = (l[oq] * inv) * u[oq];
        }
        // il-pair reduce in-wave; lanes<32 write warp slab (race-free)
#pragma unroll
        for (int oq = 0; oq < 5; ++oq) {
            float a = a5[oq];
            a += __shfl_xor(a, 32);
            if ((t & 63) < 32)
                pacc[(w * BB + bb) * ODc + (oh * 5 + oq) * 16 + d] = a;
        }
    }
    __syncthreads();
    // sum the 4 warp slabs -> per-itile partial (1280 elements)
#pragma unroll
    for (int j = 0; j < 5; ++j) {
        int e = t + j * 256;
        float s = pacc[e] + pacc[1280 + e] + pacc[2560 + e] + pacc[3840 + e];
        spart[(size_t)itile * (Bc * ODc) + b0 * ODc + e] = s;
    }
}

// ---------------------------------------------------------------- k_reduce
// Sum 144 itile-partials -> s[b][160], squash; 4 teams x 36-deep chains.
//  P==0: vsumg = v (s scaled 0.1);  P==1: vsumg += v;  P==2: out = v.
template <int P>
__global__ __launch_bounds__(1024) void k_reduce(const float* __restrict__ part,
                                                 float* __restrict__ vsumg,
                                                 float* __restrict__ out) {
    const int b = blockIdx.x;
    const int t = threadIdx.x;
    __shared__ float red4[4 * ODc];
    const int team = t >> 8, tt = t & 255;
    if (tt < ODc) {
        float s = 0.f;
        const float* pb =
            part + (size_t)team * 36 * (Bc * ODc) + (size_t)b * ODc + tt;
#pragma unroll
        for (int p = 0; p < 36; ++p) s += pb[(size_t)p * (Bc * ODc)];
        red4[team * ODc + tt] = s;
    }
    __syncthreads();
    if (t < ODc) {
        float s = red4[t] + red4[ODc + t] + red4[2 * ODc + t] + red4[3 * ODc + t];
        if (P == 0) s *= 0.1f;
        float sq = dpp16_sum(s * s);
        float v = s * (sq / ((1.f + sq) * sqrtf(sq)));
        if constexpr (P == 2) {
            out[(size_t)b * ODc + t] = v;
        } else {
            const int o = t >> 4, dd = t & 15;
            float* vp = vsumg + (size_t)b * 256 + dd * 16 + (o >= 5 ? 3 + o : o);
            if constexpr (P == 0) *vp = v;
            else                  *vp += v;
        }
    }
}

// ---------------------------------------------------------------- fallback
__global__ void __launch_bounds__(1024, 4)
digitcaps_fallback(const float* __restrict__ x, const float* __restrict__ W,
                   float* __restrict__ out) {
    const int b = blockIdx.x, t = threadIdx.x;
    const int lane = t & 63, wid = t >> 6, d = t & 15, iblk = t >> 4;
    __shared__ __align__(16) float xs[Ic * 8];
    __shared__ __align__(16) float red[16 * ODc];
    __shared__ __align__(16) float svec[ODc], vcur[ODc], vsum[ODc];
    {
        const float4* xg = (const float4*)(x + (size_t)b * (Ic * 8));
        float4* xl = (float4*)xs;
        for (int j = t; j < Ic * 2; j += 1024) xl[j] = xg[j];
    }
    if (t < ODc) vsum[t] = 0.f;
    __syncthreads();
    float acc[Oc], vsr[Oc];
    for (int it = 0; it < 3; ++it) {
#pragma unroll
        for (int o = 0; o < Oc; ++o) { acc[o] = 0.f; vsr[o] = vsum[o * 16 + d]; }
#pragma unroll 1
        for (int chk = 0; chk < 18; ++chk) {
            const int i = chk * 64 + iblk;
            const float4 xa = ((const float4*)(xs + i * 8))[0];
            const float4 xb = ((const float4*)(xs + i * 8))[1];
            const float* wb = W + (((size_t)i * Oc) * DOc + d) * 8;
            float uo[Oc];
#pragma unroll
            for (int o = 0; o < Oc; ++o) {
                const float4* wp = (const float4*)(wb + o * 128);
                float4 w0 = wp[0], w1 = wp[1];
                uo[o] = w0.x * xa.x + w0.y * xa.y + w0.z * xa.z + w0.w * xa.w +
                        w1.x * xb.x + w1.y * xb.y + w1.z * xb.z + w1.w * xb.w;
            }
            float cc[Oc];
            if (it > 0) {
#pragma unroll
                for (int o = 0; o < Oc; ++o) cc[o] = dpp16_sum(uo[o] * vsr[o]);
                float m = cc[0];
#pragma unroll
                for (int o = 1; o < Oc; ++o) m = fmaxf(m, cc[o]);
                float se = 0.f;
#pragma unroll
                for (int o = 0; o < Oc; ++o) { cc[o] = __expf(cc[o] - m); se += cc[o]; }
                float inv = 1.f / se;
#pragma unroll
                for (int o = 0; o < Oc; ++o) acc[o] += cc[o] * inv * uo[o];
            } else {
#pragma unroll
                for (int o = 0; o < Oc; ++o) acc[o] += 0.1f * uo[o];
            }
        }
#pragma unroll
        for (int o = 0; o < Oc; ++o) {
            float a = acc[o];
            a += __shfl_xor(a, 16);
            a += __shfl_xor(a, 32);
            if (lane < 16) red[wid * ODc + o * 16 + lane] = a;
        }
        __syncthreads();
        if (t < ODc) {
            float s = 0.f;
#pragma unroll
            for (int w = 0; w < 16; ++w) s += red[w * ODc + t];
            svec[t] = s;
        }
        __syncthreads();
        if (t < Oc) {
            float sq = 0.f;
#pragma unroll
            for (int dd = 0; dd < DOc; ++dd) sq += svec[t * 16 + dd] * svec[t * 16 + dd];
            float sc = sq / ((1.f + sq) * sqrtf(sq));
#pragma unroll
            for (int dd = 0; dd < DOc; ++dd) {
                float v = svec[t * 16 + dd] * sc;
                vcur[t * 16 + dd] = v;
                vsum[t * 16 + dd] += v;
            }
        }
        __syncthreads();
    }
    if (t < ODc) out[(size_t)b * ODc + t] = vcur[t];
}

// ---------------------------------------------------------------- launcher
extern "C" void kernel_launch(void* const* d_in, const int* in_sizes, int n_in,
                              void* d_out, int out_size, void* d_ws, size_t ws_size,
                              hipStream_t stream) {
    (void)in_sizes; (void)n_in; (void)out_size;
    const float* x = (const float*)d_in[0];   // [256,1152,8]
    const float* W = (const float*)d_in[1];   // [1152,10,16,8]
    float* out     = (float*)d_out;           // [256,10,16]

    const size_t PART_B = (size_t)IT * Bc * ODc * sizeof(float); // 23.59 MB
    const size_t VS_B   = (size_t)Bc * 256 * sizeof(float);      //  0.26 MB

    float* partial = (float*)d_ws;
    float* vsumg   = (float*)((char*)d_ws + PART_B);

    if (ws_size >= PART_B + VS_B) {
        hipLaunchKernelGGL((k_pass<0>), dim3(IT * BT), dim3(256), 0, stream,
                           x, W, nullptr, partial);
        hipLaunchKernelGGL((k_reduce<0>), dim3(Bc), dim3(1024), 0, stream,
                           partial, vsumg, nullptr);
        hipLaunchKernelGGL((k_pass<1>), dim3(IT * BT), dim3(256), 0, stream,
                           x, W, vsumg, partial);
        hipLaunchKernelGGL((k_reduce<1>), dim3(Bc), dim3(1024), 0, stream,
                           partial, vsumg, nullptr);
        hipLaunchKernelGGL((k_pass<1>), dim3(IT * BT), dim3(256), 0, stream,
                           x, W, vsumg, partial);
        hipLaunchKernelGGL((k_reduce<2>), dim3(Bc), dim3(1024), 0, stream,
                           partial, nullptr, out);
    } else {
        hipLaunchKernelGGL(digitcaps_fallback, dim3(Bc), dim3(1024), 0, stream,
                           x, W, out);
    }
}